// Round 6
// baseline (116.563 us; speedup 1.0000x reference)
//
#include <hip/hip_runtime.h>
#include <hip/hip_bf16.h>

// Problem: B=8, T=4096, F=512
//   score = sigmoid(feat @ W + b)            [B,T]
//   peaks = local max along T (edge-replicated, >=)
//   hlens[b] = #peaks; feat_new = peak rows compacted to front, zero tail
// Outputs concatenated in d_out: feat_new (16777216 f32) then hlens (8, as f32)
//
// R4 (resubmitted R6; two infra timeouts): K1 unchanged (bit-exact).
// K2'' 512 blocks x 512 threads (2 blocks/CU) so the per-block redundant-scan
// preamble overlaps another block's gather.
// Each block: batch b = blockIdx>>6, 64 output rows (8 waves x 8 rows).

#define T_DIM 4096
#define F_DIM 512
#define B_DIM 8

// ---------------- Kernel 1: per-row dot + sigmoid ----------------
// one wave (64 lanes) per row; lane handles 8 consecutive floats (2x float4)
__global__ void __launch_bounds__(256) score_kernel(
    const float* __restrict__ feat, const float* __restrict__ W,
    const float* __restrict__ bias, float* __restrict__ score, int nrows) {
  int gtid = blockIdx.x * blockDim.x + threadIdx.x;
  int row  = gtid >> 6;
  int lane = threadIdx.x & 63;
  if (row >= nrows) return;

  const float4* fr = (const float4*)(feat + (size_t)row * F_DIM);
  const float4* wv = (const float4*)W;
  int i0 = lane * 2;
  float4 a0 = fr[i0];
  float4 a1 = fr[i0 + 1];
  float4 w0 = wv[i0];
  float4 w1 = wv[i0 + 1];
  float sum = a0.x * w0.x + a0.y * w0.y + a0.z * w0.z + a0.w * w0.w
            + a1.x * w1.x + a1.y * w1.y + a1.z * w1.z + a1.w * w1.w;

  // wave-64 butterfly reduce
  #pragma unroll
  for (int d = 32; d > 0; d >>= 1) sum += __shfl_xor(sum, d, 64);

  if (lane == 0) {
    float x = sum + bias[0];
    score[row] = 1.0f / (1.0f + expf(-x));
  }
}

// ---------------- Kernel 2'': peaks + scan (redundant per block) + gather ---
// grid = B_DIM * 64 blocks; block = 512 threads (8 waves), 2 blocks/CU.
// block handles batch b = blockIdx.x>>6, output rows [slice*64, slice*64+64).
__global__ void __launch_bounds__(512) scan_gather_kernel(
    const float* __restrict__ feat, const float* __restrict__ score,
    float* __restrict__ out, float* __restrict__ hlens_f) {
  int b     = blockIdx.x >> 6;
  int slice = blockIdx.x & 63;

  __shared__ float s[T_DIM];          // scores; later aliased as int idx[]
  __shared__ int   wsum[8];
  __shared__ int   total_s;
  int* sidx = (int*)s;                // alias (safe: sync between uses)

  int tid  = threadIdx.x;             // 0..511
  int lane = tid & 63;
  int wave = tid >> 6;

  // load this batch's scores into LDS (16 KB, L2-resident after K1)
  {
    const float4* sb4 = (const float4*)(score + b * T_DIM);
    ((float4*)s)[tid]       = sb4[tid];
    ((float4*)s)[tid + 512] = sb4[tid + 512];
  }
  __syncthreads();

  // peak flags, 8 elements/thread
  int t0 = tid * 8;
  int flags[8];
  int cnt = 0;
  #pragma unroll
  for (int j = 0; j < 8; j++) {
    int t = t0 + j;
    float c = s[t];
    float l = (t == 0) ? c : s[t - 1];
    float r = (t == T_DIM - 1) ? c : s[t + 1];
    flags[j] = (c >= l && c >= r) ? 1 : 0;
    cnt += flags[j];
  }

  // wave-64 inclusive scan of per-thread counts
  int inc = cnt;
  #pragma unroll
  for (int d = 1; d < 64; d <<= 1) {
    int v = __shfl_up(inc, d, 64);
    if (lane >= d) inc += v;
  }
  if (lane == 63) wsum[wave] = inc;
  __syncthreads();   // all reads of s[] done; wsum[] complete

  if (tid == 0) {
    int acc = 0;
    #pragma unroll
    for (int w = 0; w < 8; w++) { int v = wsum[w]; wsum[w] = acc; acc += v; }
    total_s = acc;
    if (slice == 0) hlens_f[b] = (float)acc;   // hlens output (read as f32)
  }
  __syncthreads();

  // stable compaction: write source indices into LDS (aliases s[])
  int base = wsum[wave] + inc - cnt;  // exclusive prefix for this thread
  #pragma unroll
  for (int j = 0; j < 8; j++) {
    if (flags[j]) sidx[base++] = t0 + j;
  }
  __syncthreads();

  int total = total_s;

  // gather: 8 waves x 8 rows = 64 output rows for this slice.
  // pre-read source indices so global load addresses are ready early.
  const float* fb = feat + (size_t)b * T_DIM * F_DIM;
  float*       ob = out  + (size_t)b * T_DIM * F_DIM;
  int d0 = slice * 64 + wave * 8;
  int srcs[8];
  #pragma unroll
  for (int r = 0; r < 8; r++) {
    int d = d0 + r;
    srcs[r] = (d < total) ? sidx[d] : -1;
  }
  #pragma unroll
  for (int r = 0; r < 8; r++) {
    float4* orow = (float4*)(ob + (size_t)(d0 + r) * F_DIM);
    if (srcs[r] >= 0) {
      const float4* fr = (const float4*)(fb + (size_t)srcs[r] * F_DIM);
      float4 v0 = fr[lane];
      float4 v1 = fr[lane + 64];
      orow[lane]      = v0;
      orow[lane + 64] = v1;
    } else {
      float4 z = make_float4(0.f, 0.f, 0.f, 0.f);
      orow[lane]      = z;
      orow[lane + 64] = z;
    }
  }
}

extern "C" void kernel_launch(void* const* d_in, const int* in_sizes, int n_in,
                              void* d_out, int out_size, void* d_ws, size_t ws_size,
                              hipStream_t stream) {
  const float* feat = (const float*)d_in[0];
  const float* W    = (const float*)d_in[1];
  const float* bias = (const float*)d_in[2];

  float* out     = (float*)d_out;
  float* hlens_f = out + (size_t)B_DIM * T_DIM * F_DIM;  // tail of d_out

  float* score = (float*)d_ws;  // 32768 f32 scratch

  const int nrows = B_DIM * T_DIM;  // 32768

  // K1: scores. 4 waves/block -> 8192 blocks
  score_kernel<<<nrows / 4, 256, 0, stream>>>(feat, W, bias, score, nrows);

  // K2'': fused peaks+scan+gather. 8 batches x 64 slices = 512 blocks, 2/CU
  scan_gather_kernel<<<B_DIM * 64, 512, 0, stream>>>(feat, score, out, hlens_f);
}